// Round 8
// baseline (261.184 us; speedup 1.0000x reference)
//
#include <hip/hip_runtime.h>

// B=8, N=1024, C=1024, H=16, HD=64
// R21: occupancy experiment on the staging-rate theory. QKV: same 128x128
//      BK=64 dbuf dist-1 single-sync structure as R20, but 512-thread blocks
//      (8 waves, wave tile 64x32) -> 4 waves/SIMD at 2 blocks/CU = 2x DMA
//      concurrency, same verified conflict-free swizzle. Proj: reverted to
//      R17 single-buffer (256,3) config (best-total run). Kernels uniquely
//      named so rocprof finally attributes QKV vs proj vs attn.
//      Attention (R9) and convert unchanged.

typedef __attribute__((ext_vector_type(8))) short bf16x8;
typedef __attribute__((ext_vector_type(4))) short bf16x4;
typedef __attribute__((ext_vector_type(4))) float f32x4;

__device__ __forceinline__ short f2bf(float f) {
    union { float f; unsigned u; } x;
    x.f = f;
    unsigned r = x.u + 0x7fffu + ((x.u >> 16) & 1u);  // RNE
    return (short)(r >> 16);
}

__device__ __forceinline__ void load_lds16(const void* g, void* l) {
    __builtin_amdgcn_global_load_lds((const __attribute__((address_space(1))) unsigned*)g,
                                     (__attribute__((address_space(3))) unsigned*)l,
                                     16, 0, 0);
}

// ---------------- merged fp32 -> bf16 convert ----------------
__global__ __launch_bounds__(256) void convert_all(const float* __restrict__ x,
                                                   const float* __restrict__ wqkv,
                                                   const float* __restrict__ wproj,
                                                   short* __restrict__ xb,
                                                   short* __restrict__ wqkvb,
                                                   short* __restrict__ wprojb) {
    int i = blockIdx.x * 256 + threadIdx.x;
    const float* src;
    short* dst;
    int j;
    if (i < 2097152)      { src = x;     dst = xb;     j = i; }
    else if (i < 2883584) { src = wqkv;  dst = wqkvb;  j = i - 2097152; }
    else                  { src = wproj; dst = wprojb; j = i - 2883584; }
    float4 v = *(const float4*)(src + j * 4);
    unsigned lo = (unsigned short)f2bf(v.x) | ((unsigned)(unsigned short)f2bf(v.y) << 16);
    unsigned hi = (unsigned short)f2bf(v.z) | ((unsigned)(unsigned short)f2bf(v.w) << 16);
    uint2 p; p.x = lo; p.y = hi;
    *(uint2*)(dst + j * 4) = p;
}

// ---------------- QKV GEMM: 512-thread 128x128 dbuf dist-1 ----------------
// 8 waves (2M x 4N, wave tile 64x32), BK=64. LDS: A[2][128][64]+B[2][128][64]
// = 64KB dyn -> 2 blocks/CU = 4 waves/SIMD. One __syncthreads per K-tile.
__global__ __launch_bounds__(512, 4) void gemm_qkv5(const short* __restrict__ A,
                                                    const short* __restrict__ Bt,
                                                    short* __restrict__ q,
                                                    short* __restrict__ kk,
                                                    short* __restrict__ vt) {
    extern __shared__ short lds[];          // A[2][128][64] | B[2][128][64]
    const int K = 1024;
    constexpr int NTX = 24;
    constexpr int NWG = 64 * NTX;           // 1536
    constexpr int CHUNK = NWG / 8;

    const int bid = blockIdx.x;
    const int tile = (bid & 7) * CHUNK + (bid >> 3);   // XCD-bijective
    const int m0 = (tile / NTX) * 128;
    const int n0 = (tile % NTX) * 128;

    const int t = threadIdx.x;
    const int w = t >> 6, lane = t & 63, quad = lane >> 4, l16 = lane & 15;
    const int wm = (w >> 2) * 64, wn = (w & 3) * 32;
    const int sw = l16 & 7;

    // staging: load r covers rows r*64 + srow; source col pre-swizzled so the
    // linear global_load_lds dest yields LDS[row][slot] = G[row][slot ^ (row&7)]
    const int srow = t >> 3;                            // 0..63
    const int scol = ((t & 7) ^ (srow & 7)) * 8;
    const short* Ag = A  + (m0 + srow) * K + scol;
    const short* Bg = Bt + (n0 + srow) * K + scol;
    const int w8 = w * 8 * 64;                          // wave-uniform dest slice

    f32x4 acc[4][2];
    #pragma unroll
    for (int mi = 0; mi < 4; ++mi)
        #pragma unroll
        for (int ni = 0; ni < 2; ++ni) acc[mi][ni] = (f32x4){0.f, 0.f, 0.f, 0.f};

    // stage full tile kt into buffer d (4 gloads/wave: 2 A + 2 B, 8KB each)
#define STG(kt_, d_) do { \
    _Pragma("unroll") \
    for (int r = 0; r < 2; ++r) \
        load_lds16(Ag + r * 64 * K + (kt_) * 64, lds + (d_) * 8192 + r * 64 * 64 + w8); \
    _Pragma("unroll") \
    for (int r = 0; r < 2; ++r) \
        load_lds16(Bg + r * 64 * K + (kt_) * 64, lds + 16384 + (d_) * 8192 + r * 64 * 64 + w8); } while (0)

    STG(0, 0);
    __syncthreads();

    #pragma unroll 1
    for (int kt = 0; kt < 16; ++kt) {
        const int d = kt & 1;
        if (kt < 15) STG(kt + 1, d ^ 1);    // dist-1 prefetch, in flight all phase

        const short* Ar = lds + d * 8192;
        const short* Br = lds + 16384 + d * 8192;
        bf16x8 af[4][2], bf[2][2];
        #pragma unroll
        for (int mi = 0; mi < 4; ++mi)
            #pragma unroll
            for (int c = 0; c < 2; ++c)
                af[mi][c] = *(const bf16x8*)(Ar + (wm + mi * 16 + l16) * 64 + (((quad + 4 * c) ^ sw) * 8));
        #pragma unroll
        for (int ni = 0; ni < 2; ++ni)
            #pragma unroll
            for (int c = 0; c < 2; ++c)
                bf[ni][c] = *(const bf16x8*)(Br + (wn + ni * 16 + l16) * 64 + (((quad + 4 * c) ^ sw) * 8));
        #pragma unroll
        for (int mi = 0; mi < 4; ++mi)
            #pragma unroll
            for (int ni = 0; ni < 2; ++ni) {
                acc[mi][ni] = __builtin_amdgcn_mfma_f32_16x16x32_bf16(af[mi][0], bf[ni][0], acc[mi][ni], 0, 0, 0);
                acc[mi][ni] = __builtin_amdgcn_mfma_f32_16x16x32_bf16(af[mi][1], bf[ni][1], acc[mi][ni], 0, 0, 0);
            }
        if (kt < 15) __syncthreads();       // drains prefetch; next buf readable
    }
#undef STG

    // ---- QKV scatter epilogue ----
    const float QS = 0.125f * 1.44269504088896f;
    #pragma unroll
    for (int ni = 0; ni < 2; ++ni) {
        int col = n0 + wn + ni * 16 + l16;
        int sect = col >> 10;
        int c = col & 1023;
        int h = c >> 6, dd = c & 63;
        #pragma unroll
        for (int mi = 0; mi < 4; ++mi) {
            #pragma unroll
            for (int r = 0; r < 4; ++r) {
                int m = m0 + wm + mi * 16 + quad * 4 + r;
                int b = m >> 10, i = m & 1023;
                float v = acc[mi][ni][r];
                if (sect == 0)      q[((b * 16 + h) * 1024 + i) * 64 + dd] = f2bf(v * QS);
                else if (sect == 1) kk[((b * 16 + h) * 1024 + i) * 64 + dd] = f2bf(v);
                else                vt[((b * 16 + h) * 64 + dd) * 1024 + i] = f2bf(v);
            }
        }
    }
}

// ---------------- proj GEMM: R17 single-buffer, compiler-scheduled ----------------
// 4 waves (2x2 of 64x64), BK=64, single 32KB static LDS, 2 barriers/K-tile.
__global__ __launch_bounds__(256, 3) void gemm_proj9(const short* __restrict__ A,
                                                     const short* __restrict__ Bt,
                                                     const float* __restrict__ bias,
                                                     float* __restrict__ out) {
    __shared__ alignas(16) short As[128][64];
    __shared__ alignas(16) short Bs[128][64];
    const int K = 1024;
    constexpr int NTX = 8;
    constexpr int NWG = 64 * NTX;           // 512
    constexpr int CHUNK = NWG / 8;

    const int bid = blockIdx.x;
    const int tile = (bid & 7) * CHUNK + (bid >> 3);
    const int m0 = (tile / NTX) * 128;
    const int n0 = (tile % NTX) * 128;

    const int t = threadIdx.x;
    const int w = t >> 6, lane = t & 63, quad = lane >> 4, l16 = lane & 15;
    const int wm = (w >> 1) * 64, wn = (w & 1) * 64;
    const int sw = l16 & 7;

    const int srow = t >> 3;                            // 0..31
    const int scol = ((t & 7) ^ (srow & 7)) * 8;
    const short* Ag = A  + (m0 + srow) * K + scol;
    const short* Bg = Bt + (n0 + srow) * K + scol;
    short* const Asw = &As[w * 8][0];
    short* const Bsw = &Bs[w * 8][0];

    f32x4 acc[4][4];
    #pragma unroll
    for (int mi = 0; mi < 4; ++mi)
        #pragma unroll
        for (int ni = 0; ni < 4; ++ni) acc[mi][ni] = (f32x4){0.f, 0.f, 0.f, 0.f};

    #pragma unroll 1
    for (int kt = 0; kt < 16; ++kt) {
        __syncthreads();
        #pragma unroll
        for (int r = 0; r < 4; ++r)
            load_lds16(Ag + r * 32 * K + kt * 64, Asw + r * 32 * 64);
        #pragma unroll
        for (int r = 0; r < 4; ++r)
            load_lds16(Bg + r * 32 * K + kt * 64, Bsw + r * 32 * 64);
        __syncthreads();

        bf16x8 af[4][2], bf[4][2];
        #pragma unroll
        for (int mi = 0; mi < 4; ++mi)
            #pragma unroll
            for (int c = 0; c < 2; ++c)
                af[mi][c] = *(const bf16x8*)&As[wm + mi * 16 + l16][((quad + 4 * c) ^ sw) * 8];
        #pragma unroll
        for (int ni = 0; ni < 4; ++ni)
            #pragma unroll
            for (int c = 0; c < 2; ++c)
                bf[ni][c] = *(const bf16x8*)&Bs[wn + ni * 16 + l16][((quad + 4 * c) ^ sw) * 8];
        #pragma unroll
        for (int mi = 0; mi < 4; ++mi)
            #pragma unroll
            for (int ni = 0; ni < 4; ++ni) {
                acc[mi][ni] = __builtin_amdgcn_mfma_f32_16x16x32_bf16(af[mi][0], bf[ni][0], acc[mi][ni], 0, 0, 0);
                acc[mi][ni] = __builtin_amdgcn_mfma_f32_16x16x32_bf16(af[mi][1], bf[ni][1], acc[mi][ni], 0, 0, 0);
            }
    }

    #pragma unroll
    for (int ni = 0; ni < 4; ++ni) {
        int col = n0 + wn + ni * 16 + l16;
        float bv = bias[col];
        #pragma unroll
        for (int mi = 0; mi < 4; ++mi) {
            #pragma unroll
            for (int r = 0; r < 4; ++r) {
                int m = m0 + wm + mi * 16 + quad * 4 + r;
                out[m * 1024 + col] = acc[mi][ni][r] + bv;
            }
        }
    }
}

// ---------------- Flash attention: dbuf K/V, 1 barrier/jt, register P (R9) ----------------
__global__ __launch_bounds__(256) void attn_kernel(const short* __restrict__ q,
                                                   const short* __restrict__ k,
                                                   const short* __restrict__ vt,
                                                   short* __restrict__ ao) {
    __shared__ alignas(16) short Ks[2][64][72];
    __shared__ alignas(16) short Vs[2][64][72];

    const int bh = blockIdx.y, qt = blockIdx.x;
    const int t = threadIdx.x, w = t >> 6, lane = t & 63, quad = lane >> 4, l16 = lane & 15;
    const short* qg = q  + (bh * 1024 + qt * 128) * 64;
    const short* kg = k  + bh * 65536;
    const short* vg = vt + bh * 65536;

    bf16x8 qf[2][2];
    for (int mi = 0; mi < 2; ++mi) {
        const short* qr = qg + (w * 32 + mi * 16 + l16) * 64;
        qf[mi][0] = *(const bf16x8*)(qr + quad * 8);
        qf[mi][1] = *(const bf16x8*)(qr + 32 + quad * 8);
    }

    const int r0 = t >> 3,          c80 = (t & 7) * 8;
    const int r1 = (t + 256) >> 3,  c81 = c80;

    float rs[2] = {0.f, 0.f};
    f32x4 oaccT[2][4];
    for (int mi = 0; mi < 2; ++mi)
        for (int dt = 0; dt < 4; ++dt) oaccT[mi][dt] = (f32x4){0.f, 0.f, 0.f, 0.f};

    {
        float4 a = *(const float4*)&kg[r0 * 64 + c80];
        float4 b = *(const float4*)&kg[r1 * 64 + c81];
        float4 c = *(const float4*)&vg[r0 * 1024 + c80];
        float4 d = *(const float4*)&vg[r1 * 1024 + c81];
        *(float4*)&Ks[0][r0][c80] = a;  *(float4*)&Ks[0][r1][c81] = b;
        *(float4*)&Vs[0][r0][c80] = c;  *(float4*)&Vs[0][r1][c81] = d;
    }

    for (int jt = 0; jt < 16; ++jt) {
        const int cur = jt & 1;
        asm volatile("s_waitcnt lgkmcnt(0)" ::: "memory");
        asm volatile("s_barrier" ::: "memory");

        float4 kr0, kr1, vr0, vr1;
        if (jt < 15) {
            int jn = jt + 1;
            kr0 = *(const float4*)&kg[(jn * 64 + r0) * 64 + c80];
            kr1 = *(const float4*)&kg[(jn * 64 + r1) * 64 + c81];
            vr0 = *(const float4*)&vg[r0 * 1024 + jn * 64 + c80];
            vr1 = *(const float4*)&vg[r1 * 1024 + jn * 64 + c81];
        }

        for (int js = 0; js < 4; ++js) {
            bf16x8 kf0 = *(const bf16x8*)&Ks[cur][js * 16 + l16][quad * 8];
            bf16x8 kf1 = *(const bf16x8*)&Ks[cur][js * 16 + l16][32 + quad * 8];
            bf16x4 vtf[4];
            for (int dt = 0; dt < 4; ++dt)
                vtf[dt] = *(const bf16x4*)&Vs[cur][dt * 16 + l16][js * 16 + quad * 4];
            for (int mi = 0; mi < 2; ++mi) {
                f32x4 s = (f32x4){0.f, 0.f, 0.f, 0.f};
                s = __builtin_amdgcn_mfma_f32_16x16x32_bf16(kf0, qf[mi][0], s, 0, 0, 0);
                s = __builtin_amdgcn_mfma_f32_16x16x32_bf16(kf1, qf[mi][1], s, 0, 0, 0);
                bf16x4 pfrag;
                for (int r = 0; r < 4; ++r) {
                    float p = __builtin_amdgcn_exp2f(s[r]);
                    rs[mi] += p;
                    pfrag[r] = f2bf(p);
                }
                for (int dt = 0; dt < 4; ++dt)
                    oaccT[mi][dt] = __builtin_amdgcn_mfma_f32_16x16x16bf16_1k(
                        vtf[dt], pfrag, oaccT[mi][dt], 0, 0, 0);
            }
        }

        if (jt < 15) {
            const int nxt = cur ^ 1;
            *(float4*)&Ks[nxt][r0][c80] = kr0;  *(float4*)&Ks[nxt][r1][c81] = kr1;
            *(float4*)&Vs[nxt][r0][c80] = vr0;  *(float4*)&Vs[nxt][r1][c81] = vr1;
        }
    }

    for (int mi = 0; mi < 2; ++mi) {
        rs[mi] += __shfl_xor(rs[mi], 16, 64);
        rs[mi] += __shfl_xor(rs[mi], 32, 64);
    }

    const int b = bh >> 4, h = bh & 15;
    for (int mi = 0; mi < 2; ++mi) {
        float inv = 1.0f / rs[mi];
        int i = qt * 128 + w * 32 + mi * 16 + l16;
        short* aor = ao + (b * 1024 + i) * 1024 + h * 64;
        for (int dt = 0; dt < 4; ++dt) {
            bf16x4 o4;
            for (int r = 0; r < 4; ++r) o4[r] = f2bf(oaccT[mi][dt][r] * inv);
            *(bf16x4*)(aor + dt * 16 + quad * 4) = o4;
        }
    }
}

extern "C" void kernel_launch(void* const* d_in, const int* in_sizes, int n_in,
                              void* d_out, int out_size, void* d_ws, size_t ws_size,
                              hipStream_t stream) {
    const float* x      = (const float*)d_in[0];
    const float* w_qkv  = (const float*)d_in[1];
    const float* w_proj = (const float*)d_in[2];
    const float* b_proj = (const float*)d_in[3];
    float* out = (float*)d_out;

    char* ws = (char*)d_ws;
    short* xb     = (short*)(ws);
    short* wqkvb  = (short*)(ws + 16777216);
    short* wprojb = (short*)(ws + 23068672);
    short* qb     = (short*)(ws + 25165824);
    short* kb     = (short*)(ws + 41943040);
    short* vtb    = (short*)(ws + 58720256);
    short* aob    = (short*)(ws + 75497472);

    static bool s_init = false;
    if (!s_init) {
        hipFuncSetAttribute(reinterpret_cast<const void*>(&gemm_qkv5),
                            hipFuncAttributeMaxDynamicSharedMemorySize, 65536);
        s_init = true;
    }

    convert_all<<<12288, 256, 0, stream>>>(x, w_qkv, w_proj, xb, wqkvb, wprojb);
    // QKV: M=8192,N=3072 -> 64x24 tiles of 128x128 = 1536 blocks (512 thr)
    gemm_qkv5<<<1536, 512, 65536, stream>>>(xb, wqkvb, qb, kb, vtb);
    attn_kernel<<<dim3(8, 128), 256, 0, stream>>>(qb, kb, vtb, aob);
    // proj: M=8192,N=1024 -> 64x8 tiles of 128x128 = 512 blocks (R17 config)
    gemm_proj9<<<512, 256, 0, stream>>>(aob, wprojb, b_proj, out);
}

// Round 10
// 255.720 us; speedup vs baseline: 1.0214x; 1.0214x over previous
//
#include <hip/hip_runtime.h>

// B=8, N=1024, C=1024, H=16, HD=64
// R23: R22 minus the cvt_pk experiment (NaN fail; catalog m240 also says
//      hand-written cvt_pk is slower - abandoned, not debugged). Attention
//      reverted verbatim to the R21-passing f2bf version. Kept: proj ported
//      to the measured-best GEMM structure (gemm_qkv5's 512-thr dbuf dist-1
//      single-sync, 512 blocks = 1 round @2 blocks/CU). QKV (R21, 83us) and
//      convert frozen.

typedef __attribute__((ext_vector_type(8))) short bf16x8;
typedef __attribute__((ext_vector_type(4))) short bf16x4;
typedef __attribute__((ext_vector_type(4))) float f32x4;

__device__ __forceinline__ short f2bf(float f) {
    union { float f; unsigned u; } x;
    x.f = f;
    unsigned r = x.u + 0x7fffu + ((x.u >> 16) & 1u);  // RNE
    return (short)(r >> 16);
}

__device__ __forceinline__ void load_lds16(const void* g, void* l) {
    __builtin_amdgcn_global_load_lds((const __attribute__((address_space(1))) unsigned*)g,
                                     (__attribute__((address_space(3))) unsigned*)l,
                                     16, 0, 0);
}

// ---------------- merged fp32 -> bf16 convert ----------------
__global__ __launch_bounds__(256) void convert_all(const float* __restrict__ x,
                                                   const float* __restrict__ wqkv,
                                                   const float* __restrict__ wproj,
                                                   short* __restrict__ xb,
                                                   short* __restrict__ wqkvb,
                                                   short* __restrict__ wprojb) {
    int i = blockIdx.x * 256 + threadIdx.x;
    const float* src;
    short* dst;
    int j;
    if (i < 2097152)      { src = x;     dst = xb;     j = i; }
    else if (i < 2883584) { src = wqkv;  dst = wqkvb;  j = i - 2097152; }
    else                  { src = wproj; dst = wprojb; j = i - 2883584; }
    float4 v = *(const float4*)(src + j * 4);
    unsigned lo = (unsigned short)f2bf(v.x) | ((unsigned)(unsigned short)f2bf(v.y) << 16);
    unsigned hi = (unsigned short)f2bf(v.z) | ((unsigned)(unsigned short)f2bf(v.w) << 16);
    uint2 p; p.x = lo; p.y = hi;
    *(uint2*)(dst + j * 4) = p;
}

// ---------------- QKV GEMM: 512-thread 128x128 dbuf dist-1 (R21 best) ----------------
__global__ __launch_bounds__(512, 4) void gemm_qkv5(const short* __restrict__ A,
                                                    const short* __restrict__ Bt,
                                                    short* __restrict__ q,
                                                    short* __restrict__ kk,
                                                    short* __restrict__ vt) {
    extern __shared__ short lds[];          // A[2][128][64] | B[2][128][64]
    const int K = 1024;
    constexpr int NTX = 24;
    constexpr int NWG = 64 * NTX;           // 1536
    constexpr int CHUNK = NWG / 8;

    const int bid = blockIdx.x;
    const int tile = (bid & 7) * CHUNK + (bid >> 3);   // XCD-bijective
    const int m0 = (tile / NTX) * 128;
    const int n0 = (tile % NTX) * 128;

    const int t = threadIdx.x;
    const int w = t >> 6, lane = t & 63, quad = lane >> 4, l16 = lane & 15;
    const int wm = (w >> 2) * 64, wn = (w & 3) * 32;
    const int sw = l16 & 7;

    const int srow = t >> 3;                            // 0..63
    const int scol = ((t & 7) ^ (srow & 7)) * 8;
    const short* Ag = A  + (m0 + srow) * K + scol;
    const short* Bg = Bt + (n0 + srow) * K + scol;
    const int w8 = w * 8 * 64;

    f32x4 acc[4][2];
    #pragma unroll
    for (int mi = 0; mi < 4; ++mi)
        #pragma unroll
        for (int ni = 0; ni < 2; ++ni) acc[mi][ni] = (f32x4){0.f, 0.f, 0.f, 0.f};

#define STG(kt_, d_) do { \
    _Pragma("unroll") \
    for (int r = 0; r < 2; ++r) \
        load_lds16(Ag + r * 64 * K + (kt_) * 64, lds + (d_) * 8192 + r * 64 * 64 + w8); \
    _Pragma("unroll") \
    for (int r = 0; r < 2; ++r) \
        load_lds16(Bg + r * 64 * K + (kt_) * 64, lds + 16384 + (d_) * 8192 + r * 64 * 64 + w8); } while (0)

    STG(0, 0);
    __syncthreads();

    #pragma unroll 1
    for (int kt = 0; kt < 16; ++kt) {
        const int d = kt & 1;
        if (kt < 15) STG(kt + 1, d ^ 1);

        const short* Ar = lds + d * 8192;
        const short* Br = lds + 16384 + d * 8192;
        bf16x8 af[4][2], bf[2][2];
        #pragma unroll
        for (int mi = 0; mi < 4; ++mi)
            #pragma unroll
            for (int c = 0; c < 2; ++c)
                af[mi][c] = *(const bf16x8*)(Ar + (wm + mi * 16 + l16) * 64 + (((quad + 4 * c) ^ sw) * 8));
        #pragma unroll
        for (int ni = 0; ni < 2; ++ni)
            #pragma unroll
            for (int c = 0; c < 2; ++c)
                bf[ni][c] = *(const bf16x8*)(Br + (wn + ni * 16 + l16) * 64 + (((quad + 4 * c) ^ sw) * 8));
        #pragma unroll
        for (int mi = 0; mi < 4; ++mi)
            #pragma unroll
            for (int ni = 0; ni < 2; ++ni) {
                acc[mi][ni] = __builtin_amdgcn_mfma_f32_16x16x32_bf16(af[mi][0], bf[ni][0], acc[mi][ni], 0, 0, 0);
                acc[mi][ni] = __builtin_amdgcn_mfma_f32_16x16x32_bf16(af[mi][1], bf[ni][1], acc[mi][ni], 0, 0, 0);
            }
        if (kt < 15) __syncthreads();
    }
#undef STG

    const float QS = 0.125f * 1.44269504088896f;
    #pragma unroll
    for (int ni = 0; ni < 2; ++ni) {
        int col = n0 + wn + ni * 16 + l16;
        int sect = col >> 10;
        int c = col & 1023;
        int h = c >> 6, dd = c & 63;
        #pragma unroll
        for (int mi = 0; mi < 4; ++mi) {
            #pragma unroll
            for (int r = 0; r < 4; ++r) {
                int m = m0 + wm + mi * 16 + quad * 4 + r;
                int b = m >> 10, i = m & 1023;
                float v = acc[mi][ni][r];
                if (sect == 0)      q[((b * 16 + h) * 1024 + i) * 64 + dd] = f2bf(v * QS);
                else if (sect == 1) kk[((b * 16 + h) * 1024 + i) * 64 + dd] = f2bf(v);
                else                vt[((b * 16 + h) * 64 + dd) * 1024 + i] = f2bf(v);
            }
        }
    }
}

// ---------------- proj GEMM: same 512-thread dbuf dist-1 structure ----------------
__global__ __launch_bounds__(512, 4) void gemm_proj5(const short* __restrict__ A,
                                                     const short* __restrict__ Bt,
                                                     const float* __restrict__ bias,
                                                     float* __restrict__ out) {
    extern __shared__ short lds[];          // A[2][128][64] | B[2][128][64]
    const int K = 1024;
    constexpr int NTX = 8;
    constexpr int NWG = 64 * NTX;           // 512
    constexpr int CHUNK = NWG / 8;

    const int bid = blockIdx.x;
    const int tile = (bid & 7) * CHUNK + (bid >> 3);
    const int m0 = (tile / NTX) * 128;
    const int n0 = (tile % NTX) * 128;

    const int t = threadIdx.x;
    const int w = t >> 6, lane = t & 63, quad = lane >> 4, l16 = lane & 15;
    const int wm = (w >> 2) * 64, wn = (w & 3) * 32;
    const int sw = l16 & 7;

    const int srow = t >> 3;
    const int scol = ((t & 7) ^ (srow & 7)) * 8;
    const short* Ag = A  + (m0 + srow) * K + scol;
    const short* Bg = Bt + (n0 + srow) * K + scol;
    const int w8 = w * 8 * 64;

    f32x4 acc[4][2];
    #pragma unroll
    for (int mi = 0; mi < 4; ++mi)
        #pragma unroll
        for (int ni = 0; ni < 2; ++ni) acc[mi][ni] = (f32x4){0.f, 0.f, 0.f, 0.f};

#define STG(kt_, d_) do { \
    _Pragma("unroll") \
    for (int r = 0; r < 2; ++r) \
        load_lds16(Ag + r * 64 * K + (kt_) * 64, lds + (d_) * 8192 + r * 64 * 64 + w8); \
    _Pragma("unroll") \
    for (int r = 0; r < 2; ++r) \
        load_lds16(Bg + r * 64 * K + (kt_) * 64, lds + 16384 + (d_) * 8192 + r * 64 * 64 + w8); } while (0)

    STG(0, 0);
    __syncthreads();

    #pragma unroll 1
    for (int kt = 0; kt < 16; ++kt) {
        const int d = kt & 1;
        if (kt < 15) STG(kt + 1, d ^ 1);

        const short* Ar = lds + d * 8192;
        const short* Br = lds + 16384 + d * 8192;
        bf16x8 af[4][2], bf[2][2];
        #pragma unroll
        for (int mi = 0; mi < 4; ++mi)
            #pragma unroll
            for (int c = 0; c < 2; ++c)
                af[mi][c] = *(const bf16x8*)(Ar + (wm + mi * 16 + l16) * 64 + (((quad + 4 * c) ^ sw) * 8));
        #pragma unroll
        for (int ni = 0; ni < 2; ++ni)
            #pragma unroll
            for (int c = 0; c < 2; ++c)
                bf[ni][c] = *(const bf16x8*)(Br + (wn + ni * 16 + l16) * 64 + (((quad + 4 * c) ^ sw) * 8));
        #pragma unroll
        for (int mi = 0; mi < 4; ++mi)
            #pragma unroll
            for (int ni = 0; ni < 2; ++ni) {
                acc[mi][ni] = __builtin_amdgcn_mfma_f32_16x16x32_bf16(af[mi][0], bf[ni][0], acc[mi][ni], 0, 0, 0);
                acc[mi][ni] = __builtin_amdgcn_mfma_f32_16x16x32_bf16(af[mi][1], bf[ni][1], acc[mi][ni], 0, 0, 0);
            }
        if (kt < 15) __syncthreads();
    }
#undef STG

    #pragma unroll
    for (int ni = 0; ni < 2; ++ni) {
        int col = n0 + wn + ni * 16 + l16;
        float bv = bias[col];
        #pragma unroll
        for (int mi = 0; mi < 4; ++mi) {
            #pragma unroll
            for (int r = 0; r < 4; ++r) {
                int m = m0 + wm + mi * 16 + quad * 4 + r;
                out[m * 1024 + col] = acc[mi][ni][r] + bv;
            }
        }
    }
}

// ---------------- Flash attention: dbuf K/V, 1 barrier/jt, register P (R9/R21) ----------------
__global__ __launch_bounds__(256) void attn_kernel(const short* __restrict__ q,
                                                   const short* __restrict__ k,
                                                   const short* __restrict__ vt,
                                                   short* __restrict__ ao) {
    __shared__ alignas(16) short Ks[2][64][72];
    __shared__ alignas(16) short Vs[2][64][72];

    const int bh = blockIdx.y, qt = blockIdx.x;
    const int t = threadIdx.x, w = t >> 6, lane = t & 63, quad = lane >> 4, l16 = lane & 15;
    const short* qg = q  + (bh * 1024 + qt * 128) * 64;
    const short* kg = k  + bh * 65536;
    const short* vg = vt + bh * 65536;

    bf16x8 qf[2][2];
    for (int mi = 0; mi < 2; ++mi) {
        const short* qr = qg + (w * 32 + mi * 16 + l16) * 64;
        qf[mi][0] = *(const bf16x8*)(qr + quad * 8);
        qf[mi][1] = *(const bf16x8*)(qr + 32 + quad * 8);
    }

    const int r0 = t >> 3,          c80 = (t & 7) * 8;
    const int r1 = (t + 256) >> 3,  c81 = c80;

    float rs[2] = {0.f, 0.f};
    f32x4 oaccT[2][4];
    for (int mi = 0; mi < 2; ++mi)
        for (int dt = 0; dt < 4; ++dt) oaccT[mi][dt] = (f32x4){0.f, 0.f, 0.f, 0.f};

    {
        float4 a = *(const float4*)&kg[r0 * 64 + c80];
        float4 b = *(const float4*)&kg[r1 * 64 + c81];
        float4 c = *(const float4*)&vg[r0 * 1024 + c80];
        float4 d = *(const float4*)&vg[r1 * 1024 + c81];
        *(float4*)&Ks[0][r0][c80] = a;  *(float4*)&Ks[0][r1][c81] = b;
        *(float4*)&Vs[0][r0][c80] = c;  *(float4*)&Vs[0][r1][c81] = d;
    }

    for (int jt = 0; jt < 16; ++jt) {
        const int cur = jt & 1;
        asm volatile("s_waitcnt lgkmcnt(0)" ::: "memory");
        asm volatile("s_barrier" ::: "memory");

        float4 kr0, kr1, vr0, vr1;
        if (jt < 15) {
            int jn = jt + 1;
            kr0 = *(const float4*)&kg[(jn * 64 + r0) * 64 + c80];
            kr1 = *(const float4*)&kg[(jn * 64 + r1) * 64 + c81];
            vr0 = *(const float4*)&vg[r0 * 1024 + jn * 64 + c80];
            vr1 = *(const float4*)&vg[r1 * 1024 + jn * 64 + c81];
        }

        for (int js = 0; js < 4; ++js) {
            bf16x8 kf0 = *(const bf16x8*)&Ks[cur][js * 16 + l16][quad * 8];
            bf16x8 kf1 = *(const bf16x8*)&Ks[cur][js * 16 + l16][32 + quad * 8];
            bf16x4 vtf[4];
            for (int dt = 0; dt < 4; ++dt)
                vtf[dt] = *(const bf16x4*)&Vs[cur][dt * 16 + l16][js * 16 + quad * 4];
            for (int mi = 0; mi < 2; ++mi) {
                f32x4 s = (f32x4){0.f, 0.f, 0.f, 0.f};
                s = __builtin_amdgcn_mfma_f32_16x16x32_bf16(kf0, qf[mi][0], s, 0, 0, 0);
                s = __builtin_amdgcn_mfma_f32_16x16x32_bf16(kf1, qf[mi][1], s, 0, 0, 0);
                bf16x4 pfrag;
                for (int r = 0; r < 4; ++r) {
                    float p = __builtin_amdgcn_exp2f(s[r]);
                    rs[mi] += p;
                    pfrag[r] = f2bf(p);
                }
                for (int dt = 0; dt < 4; ++dt)
                    oaccT[mi][dt] = __builtin_amdgcn_mfma_f32_16x16x16bf16_1k(
                        vtf[dt], pfrag, oaccT[mi][dt], 0, 0, 0);
            }
        }

        if (jt < 15) {
            const int nxt = cur ^ 1;
            *(float4*)&Ks[nxt][r0][c80] = kr0;  *(float4*)&Ks[nxt][r1][c81] = kr1;
            *(float4*)&Vs[nxt][r0][c80] = vr0;  *(float4*)&Vs[nxt][r1][c81] = vr1;
        }
    }

    for (int mi = 0; mi < 2; ++mi) {
        rs[mi] += __shfl_xor(rs[mi], 16, 64);
        rs[mi] += __shfl_xor(rs[mi], 32, 64);
    }

    const int b = bh >> 4, h = bh & 15;
    for (int mi = 0; mi < 2; ++mi) {
        float inv = 1.0f / rs[mi];
        int i = qt * 128 + w * 32 + mi * 16 + l16;
        short* aor = ao + (b * 1024 + i) * 1024 + h * 64;
        for (int dt = 0; dt < 4; ++dt) {
            bf16x4 o4;
            for (int r = 0; r < 4; ++r) o4[r] = f2bf(oaccT[mi][dt][r] * inv);
            *(bf16x4*)(aor + dt * 16 + quad * 4) = o4;
        }
    }
}

extern "C" void kernel_launch(void* const* d_in, const int* in_sizes, int n_in,
                              void* d_out, int out_size, void* d_ws, size_t ws_size,
                              hipStream_t stream) {
    const float* x      = (const float*)d_in[0];
    const float* w_qkv  = (const float*)d_in[1];
    const float* w_proj = (const float*)d_in[2];
    const float* b_proj = (const float*)d_in[3];
    float* out = (float*)d_out;

    char* ws = (char*)d_ws;
    short* xb     = (short*)(ws);
    short* wqkvb  = (short*)(ws + 16777216);
    short* wprojb = (short*)(ws + 23068672);
    short* qb     = (short*)(ws + 25165824);
    short* kb     = (short*)(ws + 41943040);
    short* vtb    = (short*)(ws + 58720256);
    short* aob    = (short*)(ws + 75497472);

    static bool s_init = false;
    if (!s_init) {
        hipFuncSetAttribute(reinterpret_cast<const void*>(&gemm_qkv5),
                            hipFuncAttributeMaxDynamicSharedMemorySize, 65536);
        hipFuncSetAttribute(reinterpret_cast<const void*>(&gemm_proj5),
                            hipFuncAttributeMaxDynamicSharedMemorySize, 65536);
        s_init = true;
    }

    convert_all<<<12288, 256, 0, stream>>>(x, w_qkv, w_proj, xb, wqkvb, wprojb);
    gemm_qkv5<<<1536, 512, 65536, stream>>>(xb, wqkvb, qb, kb, vtb);
    attn_kernel<<<dim3(8, 128), 256, 0, stream>>>(qb, kb, vtb, aob);
    gemm_proj5<<<512, 512, 65536, stream>>>(aob, wprojb, b_proj, out);
}

// Round 11
// 240.732 us; speedup vs baseline: 1.0850x; 1.0623x over previous
//
#include <hip/hip_runtime.h>
#include <hip/hip_bf16.h>

// B=8, N=1024, C=1024, H=16, HD=64
// R24: attn-only round (QKV/proj/convert frozen at R23 = best-verified).
//      (1) softmax P->bf16 and epilogue conversions use compiler-generated
//          __float2bfloat16 casts (RNE, same numerics) instead of the 5-instr
//          manual-RNE bit sequence -> softmax VALU roughly halves. (m240:
//          compiler cast path is the fast one; hand-written cvt_pk asm was
//          the R22 NaN + measured regression.)
//      (2) T5 s_setprio(1) around QK and PV MFMA clusters (m191: +4-7% on
//          attn, the one technique with a measured positive in this regime).

typedef __attribute__((ext_vector_type(8))) short bf16x8;
typedef __attribute__((ext_vector_type(4))) short bf16x4;
typedef __attribute__((ext_vector_type(4))) float f32x4;

__device__ __forceinline__ short f2bf(float f) {
    union { float f; unsigned u; } x;
    x.f = f;
    unsigned r = x.u + 0x7fffu + ((x.u >> 16) & 1u);  // RNE
    return (short)(r >> 16);
}

__device__ __forceinline__ short f2bf_cvt(float f) {
    __hip_bfloat16 h = __float2bfloat16(f);           // compiler RNE cast
    return *reinterpret_cast<short*>(&h);
}

__device__ __forceinline__ void load_lds16(const void* g, void* l) {
    __builtin_amdgcn_global_load_lds((const __attribute__((address_space(1))) unsigned*)g,
                                     (__attribute__((address_space(3))) unsigned*)l,
                                     16, 0, 0);
}

// ---------------- merged fp32 -> bf16 convert (frozen) ----------------
__global__ __launch_bounds__(256) void convert_all(const float* __restrict__ x,
                                                   const float* __restrict__ wqkv,
                                                   const float* __restrict__ wproj,
                                                   short* __restrict__ xb,
                                                   short* __restrict__ wqkvb,
                                                   short* __restrict__ wprojb) {
    int i = blockIdx.x * 256 + threadIdx.x;
    const float* src;
    short* dst;
    int j;
    if (i < 2097152)      { src = x;     dst = xb;     j = i; }
    else if (i < 2883584) { src = wqkv;  dst = wqkvb;  j = i - 2097152; }
    else                  { src = wproj; dst = wprojb; j = i - 2883584; }
    float4 v = *(const float4*)(src + j * 4);
    unsigned lo = (unsigned short)f2bf(v.x) | ((unsigned)(unsigned short)f2bf(v.y) << 16);
    unsigned hi = (unsigned short)f2bf(v.z) | ((unsigned)(unsigned short)f2bf(v.w) << 16);
    uint2 p; p.x = lo; p.y = hi;
    *(uint2*)(dst + j * 4) = p;
}

// ---------------- QKV GEMM: 512-thread 128x128 dbuf dist-1 (frozen) ----------------
__global__ __launch_bounds__(512, 4) void gemm_qkv5(const short* __restrict__ A,
                                                    const short* __restrict__ Bt,
                                                    short* __restrict__ q,
                                                    short* __restrict__ kk,
                                                    short* __restrict__ vt) {
    extern __shared__ short lds[];          // A[2][128][64] | B[2][128][64]
    const int K = 1024;
    constexpr int NTX = 24;
    constexpr int NWG = 64 * NTX;           // 1536
    constexpr int CHUNK = NWG / 8;

    const int bid = blockIdx.x;
    const int tile = (bid & 7) * CHUNK + (bid >> 3);   // XCD-bijective
    const int m0 = (tile / NTX) * 128;
    const int n0 = (tile % NTX) * 128;

    const int t = threadIdx.x;
    const int w = t >> 6, lane = t & 63, quad = lane >> 4, l16 = lane & 15;
    const int wm = (w >> 2) * 64, wn = (w & 3) * 32;
    const int sw = l16 & 7;

    const int srow = t >> 3;                            // 0..63
    const int scol = ((t & 7) ^ (srow & 7)) * 8;
    const short* Ag = A  + (m0 + srow) * K + scol;
    const short* Bg = Bt + (n0 + srow) * K + scol;
    const int w8 = w * 8 * 64;

    f32x4 acc[4][2];
    #pragma unroll
    for (int mi = 0; mi < 4; ++mi)
        #pragma unroll
        for (int ni = 0; ni < 2; ++ni) acc[mi][ni] = (f32x4){0.f, 0.f, 0.f, 0.f};

#define STG(kt_, d_) do { \
    _Pragma("unroll") \
    for (int r = 0; r < 2; ++r) \
        load_lds16(Ag + r * 64 * K + (kt_) * 64, lds + (d_) * 8192 + r * 64 * 64 + w8); \
    _Pragma("unroll") \
    for (int r = 0; r < 2; ++r) \
        load_lds16(Bg + r * 64 * K + (kt_) * 64, lds + 16384 + (d_) * 8192 + r * 64 * 64 + w8); } while (0)

    STG(0, 0);
    __syncthreads();

    #pragma unroll 1
    for (int kt = 0; kt < 16; ++kt) {
        const int d = kt & 1;
        if (kt < 15) STG(kt + 1, d ^ 1);

        const short* Ar = lds + d * 8192;
        const short* Br = lds + 16384 + d * 8192;
        bf16x8 af[4][2], bf[2][2];
        #pragma unroll
        for (int mi = 0; mi < 4; ++mi)
            #pragma unroll
            for (int c = 0; c < 2; ++c)
                af[mi][c] = *(const bf16x8*)(Ar + (wm + mi * 16 + l16) * 64 + (((quad + 4 * c) ^ sw) * 8));
        #pragma unroll
        for (int ni = 0; ni < 2; ++ni)
            #pragma unroll
            for (int c = 0; c < 2; ++c)
                bf[ni][c] = *(const bf16x8*)(Br + (wn + ni * 16 + l16) * 64 + (((quad + 4 * c) ^ sw) * 8));
        #pragma unroll
        for (int mi = 0; mi < 4; ++mi)
            #pragma unroll
            for (int ni = 0; ni < 2; ++ni) {
                acc[mi][ni] = __builtin_amdgcn_mfma_f32_16x16x32_bf16(af[mi][0], bf[ni][0], acc[mi][ni], 0, 0, 0);
                acc[mi][ni] = __builtin_amdgcn_mfma_f32_16x16x32_bf16(af[mi][1], bf[ni][1], acc[mi][ni], 0, 0, 0);
            }
        if (kt < 15) __syncthreads();
    }
#undef STG

    const float QS = 0.125f * 1.44269504088896f;
    #pragma unroll
    for (int ni = 0; ni < 2; ++ni) {
        int col = n0 + wn + ni * 16 + l16;
        int sect = col >> 10;
        int c = col & 1023;
        int h = c >> 6, dd = c & 63;
        #pragma unroll
        for (int mi = 0; mi < 4; ++mi) {
            #pragma unroll
            for (int r = 0; r < 4; ++r) {
                int m = m0 + wm + mi * 16 + quad * 4 + r;
                int b = m >> 10, i = m & 1023;
                float v = acc[mi][ni][r];
                if (sect == 0)      q[((b * 16 + h) * 1024 + i) * 64 + dd] = f2bf(v * QS);
                else if (sect == 1) kk[((b * 16 + h) * 1024 + i) * 64 + dd] = f2bf(v);
                else                vt[((b * 16 + h) * 64 + dd) * 1024 + i] = f2bf(v);
            }
        }
    }
}

// ---------------- proj GEMM: 512-thread dbuf dist-1 (frozen) ----------------
__global__ __launch_bounds__(512, 4) void gemm_proj5(const short* __restrict__ A,
                                                     const short* __restrict__ Bt,
                                                     const float* __restrict__ bias,
                                                     float* __restrict__ out) {
    extern __shared__ short lds[];          // A[2][128][64] | B[2][128][64]
    const int K = 1024;
    constexpr int NTX = 8;
    constexpr int NWG = 64 * NTX;           // 512
    constexpr int CHUNK = NWG / 8;

    const int bid = blockIdx.x;
    const int tile = (bid & 7) * CHUNK + (bid >> 3);
    const int m0 = (tile / NTX) * 128;
    const int n0 = (tile % NTX) * 128;

    const int t = threadIdx.x;
    const int w = t >> 6, lane = t & 63, quad = lane >> 4, l16 = lane & 15;
    const int wm = (w >> 2) * 64, wn = (w & 3) * 32;
    const int sw = l16 & 7;

    const int srow = t >> 3;
    const int scol = ((t & 7) ^ (srow & 7)) * 8;
    const short* Ag = A  + (m0 + srow) * K + scol;
    const short* Bg = Bt + (n0 + srow) * K + scol;
    const int w8 = w * 8 * 64;

    f32x4 acc[4][2];
    #pragma unroll
    for (int mi = 0; mi < 4; ++mi)
        #pragma unroll
        for (int ni = 0; ni < 2; ++ni) acc[mi][ni] = (f32x4){0.f, 0.f, 0.f, 0.f};

#define STG(kt_, d_) do { \
    _Pragma("unroll") \
    for (int r = 0; r < 2; ++r) \
        load_lds16(Ag + r * 64 * K + (kt_) * 64, lds + (d_) * 8192 + r * 64 * 64 + w8); \
    _Pragma("unroll") \
    for (int r = 0; r < 2; ++r) \
        load_lds16(Bg + r * 64 * K + (kt_) * 64, lds + 16384 + (d_) * 8192 + r * 64 * 64 + w8); } while (0)

    STG(0, 0);
    __syncthreads();

    #pragma unroll 1
    for (int kt = 0; kt < 16; ++kt) {
        const int d = kt & 1;
        if (kt < 15) STG(kt + 1, d ^ 1);

        const short* Ar = lds + d * 8192;
        const short* Br = lds + 16384 + d * 8192;
        bf16x8 af[4][2], bf[2][2];
        #pragma unroll
        for (int mi = 0; mi < 4; ++mi)
            #pragma unroll
            for (int c = 0; c < 2; ++c)
                af[mi][c] = *(const bf16x8*)(Ar + (wm + mi * 16 + l16) * 64 + (((quad + 4 * c) ^ sw) * 8));
        #pragma unroll
        for (int ni = 0; ni < 2; ++ni)
            #pragma unroll
            for (int c = 0; c < 2; ++c)
                bf[ni][c] = *(const bf16x8*)(Br + (wn + ni * 16 + l16) * 64 + (((quad + 4 * c) ^ sw) * 8));
        #pragma unroll
        for (int mi = 0; mi < 4; ++mi)
            #pragma unroll
            for (int ni = 0; ni < 2; ++ni) {
                acc[mi][ni] = __builtin_amdgcn_mfma_f32_16x16x32_bf16(af[mi][0], bf[ni][0], acc[mi][ni], 0, 0, 0);
                acc[mi][ni] = __builtin_amdgcn_mfma_f32_16x16x32_bf16(af[mi][1], bf[ni][1], acc[mi][ni], 0, 0, 0);
            }
        if (kt < 15) __syncthreads();
    }
#undef STG

    #pragma unroll
    for (int ni = 0; ni < 2; ++ni) {
        int col = n0 + wn + ni * 16 + l16;
        float bv = bias[col];
        #pragma unroll
        for (int mi = 0; mi < 4; ++mi) {
            #pragma unroll
            for (int r = 0; r < 4; ++r) {
                int m = m0 + wm + mi * 16 + quad * 4 + r;
                out[m * 1024 + col] = acc[mi][ni][r] + bv;
            }
        }
    }
}

// ---------------- Flash attention: dbuf K/V, register P, cast-bf16 + setprio ----------------
__global__ __launch_bounds__(256) void attn_kernel(const short* __restrict__ q,
                                                   const short* __restrict__ k,
                                                   const short* __restrict__ vt,
                                                   short* __restrict__ ao) {
    __shared__ alignas(16) short Ks[2][64][72];
    __shared__ alignas(16) short Vs[2][64][72];

    const int bh = blockIdx.y, qt = blockIdx.x;
    const int t = threadIdx.x, w = t >> 6, lane = t & 63, quad = lane >> 4, l16 = lane & 15;
    const short* qg = q  + (bh * 1024 + qt * 128) * 64;
    const short* kg = k  + bh * 65536;
    const short* vg = vt + bh * 65536;

    bf16x8 qf[2][2];
    for (int mi = 0; mi < 2; ++mi) {
        const short* qr = qg + (w * 32 + mi * 16 + l16) * 64;
        qf[mi][0] = *(const bf16x8*)(qr + quad * 8);
        qf[mi][1] = *(const bf16x8*)(qr + 32 + quad * 8);
    }

    const int r0 = t >> 3,          c80 = (t & 7) * 8;
    const int r1 = (t + 256) >> 3,  c81 = c80;

    float rs[2] = {0.f, 0.f};
    f32x4 oaccT[2][4];
    for (int mi = 0; mi < 2; ++mi)
        for (int dt = 0; dt < 4; ++dt) oaccT[mi][dt] = (f32x4){0.f, 0.f, 0.f, 0.f};

    {
        float4 a = *(const float4*)&kg[r0 * 64 + c80];
        float4 b = *(const float4*)&kg[r1 * 64 + c81];
        float4 c = *(const float4*)&vg[r0 * 1024 + c80];
        float4 d = *(const float4*)&vg[r1 * 1024 + c81];
        *(float4*)&Ks[0][r0][c80] = a;  *(float4*)&Ks[0][r1][c81] = b;
        *(float4*)&Vs[0][r0][c80] = c;  *(float4*)&Vs[0][r1][c81] = d;
    }

    for (int jt = 0; jt < 16; ++jt) {
        const int cur = jt & 1;
        asm volatile("s_waitcnt lgkmcnt(0)" ::: "memory");
        asm volatile("s_barrier" ::: "memory");

        float4 kr0, kr1, vr0, vr1;
        if (jt < 15) {
            int jn = jt + 1;
            kr0 = *(const float4*)&kg[(jn * 64 + r0) * 64 + c80];
            kr1 = *(const float4*)&kg[(jn * 64 + r1) * 64 + c81];
            vr0 = *(const float4*)&vg[r0 * 1024 + jn * 64 + c80];
            vr1 = *(const float4*)&vg[r1 * 1024 + jn * 64 + c81];
        }

        for (int js = 0; js < 4; ++js) {
            bf16x8 kf0 = *(const bf16x8*)&Ks[cur][js * 16 + l16][quad * 8];
            bf16x8 kf1 = *(const bf16x8*)&Ks[cur][js * 16 + l16][32 + quad * 8];
            bf16x4 vtf[4];
            for (int dt = 0; dt < 4; ++dt)
                vtf[dt] = *(const bf16x4*)&Vs[cur][dt * 16 + l16][js * 16 + quad * 4];
            for (int mi = 0; mi < 2; ++mi) {
                f32x4 s = (f32x4){0.f, 0.f, 0.f, 0.f};
                __builtin_amdgcn_s_setprio(1);
                s = __builtin_amdgcn_mfma_f32_16x16x32_bf16(kf0, qf[mi][0], s, 0, 0, 0);
                s = __builtin_amdgcn_mfma_f32_16x16x32_bf16(kf1, qf[mi][1], s, 0, 0, 0);
                __builtin_amdgcn_s_setprio(0);
                bf16x4 pfrag;
                #pragma unroll
                for (int r = 0; r < 4; ++r) {
                    float p = __builtin_amdgcn_exp2f(s[r]);
                    rs[mi] += p;
                    pfrag[r] = f2bf_cvt(p);          // compiler RNE cast (packs)
                }
                __builtin_amdgcn_s_setprio(1);
                #pragma unroll
                for (int dt = 0; dt < 4; ++dt)
                    oaccT[mi][dt] = __builtin_amdgcn_mfma_f32_16x16x16bf16_1k(
                        vtf[dt], pfrag, oaccT[mi][dt], 0, 0, 0);
                __builtin_amdgcn_s_setprio(0);
            }
        }

        if (jt < 15) {
            const int nxt = cur ^ 1;
            *(float4*)&Ks[nxt][r0][c80] = kr0;  *(float4*)&Ks[nxt][r1][c81] = kr1;
            *(float4*)&Vs[nxt][r0][c80] = vr0;  *(float4*)&Vs[nxt][r1][c81] = vr1;
        }
    }

    for (int mi = 0; mi < 2; ++mi) {
        rs[mi] += __shfl_xor(rs[mi], 16, 64);
        rs[mi] += __shfl_xor(rs[mi], 32, 64);
    }

    const int b = bh >> 4, h = bh & 15;
    for (int mi = 0; mi < 2; ++mi) {
        float inv = 1.0f / rs[mi];
        int i = qt * 128 + w * 32 + mi * 16 + l16;
        short* aor = ao + (b * 1024 + i) * 1024 + h * 64;
        for (int dt = 0; dt < 4; ++dt) {
            bf16x4 o4;
            #pragma unroll
            for (int r = 0; r < 4; ++r) o4[r] = f2bf_cvt(oaccT[mi][dt][r] * inv);
            *(bf16x4*)(aor + dt * 16 + quad * 4) = o4;
        }
    }
}

extern "C" void kernel_launch(void* const* d_in, const int* in_sizes, int n_in,
                              void* d_out, int out_size, void* d_ws, size_t ws_size,
                              hipStream_t stream) {
    const float* x      = (const float*)d_in[0];
    const float* w_qkv  = (const float*)d_in[1];
    const float* w_proj = (const float*)d_in[2];
    const float* b_proj = (const float*)d_in[3];
    float* out = (float*)d_out;

    char* ws = (char*)d_ws;
    short* xb     = (short*)(ws);
    short* wqkvb  = (short*)(ws + 16777216);
    short* wprojb = (short*)(ws + 23068672);
    short* qb     = (short*)(ws + 25165824);
    short* kb     = (short*)(ws + 41943040);
    short* vtb    = (short*)(ws + 58720256);
    short* aob    = (short*)(ws + 75497472);

    static bool s_init = false;
    if (!s_init) {
        hipFuncSetAttribute(reinterpret_cast<const void*>(&gemm_qkv5),
                            hipFuncAttributeMaxDynamicSharedMemorySize, 65536);
        hipFuncSetAttribute(reinterpret_cast<const void*>(&gemm_proj5),
                            hipFuncAttributeMaxDynamicSharedMemorySize, 65536);
        s_init = true;
    }

    convert_all<<<12288, 256, 0, stream>>>(x, w_qkv, w_proj, xb, wqkvb, wprojb);
    gemm_qkv5<<<1536, 512, 65536, stream>>>(xb, wqkvb, qb, kb, vtb);
    attn_kernel<<<dim3(8, 128), 256, 0, stream>>>(qb, kb, vtb, aob);
    gemm_proj5<<<512, 512, 65536, stream>>>(aob, wprojb, b_proj, out);
}

// Round 12
// 237.279 us; speedup vs baseline: 1.1008x; 1.0146x over previous
//
#include <hip/hip_runtime.h>
#include <hip/hip_bf16.h>

// B=8, N=1024, C=1024, H=16, HD=64
// R25: attn Q-tile doubling. QBLK 128 -> 256 via 512-thread blocks (8 waves
//      x 32 q-rows), grid (4,128): K/V global->LDS staging per bh halves
//      (8 -> 4 blocks re-reading each bh's K/V), LDS writes halve, total
//      barrier events halve; MFMA/VALU per work unchanged; occupancy
//      identical (2 blk/CU x 512 thr = 16 waves/CU, LDS 73.7KB/CU fits).
//      R24's cast-bf16 softmax + setprio kept. QKV/proj/convert frozen.

typedef __attribute__((ext_vector_type(8))) short bf16x8;
typedef __attribute__((ext_vector_type(4))) short bf16x4;
typedef __attribute__((ext_vector_type(4))) float f32x4;

__device__ __forceinline__ short f2bf(float f) {
    union { float f; unsigned u; } x;
    x.f = f;
    unsigned r = x.u + 0x7fffu + ((x.u >> 16) & 1u);  // RNE
    return (short)(r >> 16);
}

__device__ __forceinline__ short f2bf_cvt(float f) {
    __hip_bfloat16 h = __float2bfloat16(f);           // compiler RNE cast
    return *reinterpret_cast<short*>(&h);
}

__device__ __forceinline__ void load_lds16(const void* g, void* l) {
    __builtin_amdgcn_global_load_lds((const __attribute__((address_space(1))) unsigned*)g,
                                     (__attribute__((address_space(3))) unsigned*)l,
                                     16, 0, 0);
}

// ---------------- merged fp32 -> bf16 convert (frozen) ----------------
__global__ __launch_bounds__(256) void convert_all(const float* __restrict__ x,
                                                   const float* __restrict__ wqkv,
                                                   const float* __restrict__ wproj,
                                                   short* __restrict__ xb,
                                                   short* __restrict__ wqkvb,
                                                   short* __restrict__ wprojb) {
    int i = blockIdx.x * 256 + threadIdx.x;
    const float* src;
    short* dst;
    int j;
    if (i < 2097152)      { src = x;     dst = xb;     j = i; }
    else if (i < 2883584) { src = wqkv;  dst = wqkvb;  j = i - 2097152; }
    else                  { src = wproj; dst = wprojb; j = i - 2883584; }
    float4 v = *(const float4*)(src + j * 4);
    unsigned lo = (unsigned short)f2bf(v.x) | ((unsigned)(unsigned short)f2bf(v.y) << 16);
    unsigned hi = (unsigned short)f2bf(v.z) | ((unsigned)(unsigned short)f2bf(v.w) << 16);
    uint2 p; p.x = lo; p.y = hi;
    *(uint2*)(dst + j * 4) = p;
}

// ---------------- QKV GEMM: 512-thread 128x128 dbuf dist-1 (frozen) ----------------
__global__ __launch_bounds__(512, 4) void gemm_qkv5(const short* __restrict__ A,
                                                    const short* __restrict__ Bt,
                                                    short* __restrict__ q,
                                                    short* __restrict__ kk,
                                                    short* __restrict__ vt) {
    extern __shared__ short lds[];          // A[2][128][64] | B[2][128][64]
    const int K = 1024;
    constexpr int NTX = 24;
    constexpr int NWG = 64 * NTX;           // 1536
    constexpr int CHUNK = NWG / 8;

    const int bid = blockIdx.x;
    const int tile = (bid & 7) * CHUNK + (bid >> 3);   // XCD-bijective
    const int m0 = (tile / NTX) * 128;
    const int n0 = (tile % NTX) * 128;

    const int t = threadIdx.x;
    const int w = t >> 6, lane = t & 63, quad = lane >> 4, l16 = lane & 15;
    const int wm = (w >> 2) * 64, wn = (w & 3) * 32;
    const int sw = l16 & 7;

    const int srow = t >> 3;                            // 0..63
    const int scol = ((t & 7) ^ (srow & 7)) * 8;
    const short* Ag = A  + (m0 + srow) * K + scol;
    const short* Bg = Bt + (n0 + srow) * K + scol;
    const int w8 = w * 8 * 64;

    f32x4 acc[4][2];
    #pragma unroll
    for (int mi = 0; mi < 4; ++mi)
        #pragma unroll
        for (int ni = 0; ni < 2; ++ni) acc[mi][ni] = (f32x4){0.f, 0.f, 0.f, 0.f};

#define STG(kt_, d_) do { \
    _Pragma("unroll") \
    for (int r = 0; r < 2; ++r) \
        load_lds16(Ag + r * 64 * K + (kt_) * 64, lds + (d_) * 8192 + r * 64 * 64 + w8); \
    _Pragma("unroll") \
    for (int r = 0; r < 2; ++r) \
        load_lds16(Bg + r * 64 * K + (kt_) * 64, lds + 16384 + (d_) * 8192 + r * 64 * 64 + w8); } while (0)

    STG(0, 0);
    __syncthreads();

    #pragma unroll 1
    for (int kt = 0; kt < 16; ++kt) {
        const int d = kt & 1;
        if (kt < 15) STG(kt + 1, d ^ 1);

        const short* Ar = lds + d * 8192;
        const short* Br = lds + 16384 + d * 8192;
        bf16x8 af[4][2], bf[2][2];
        #pragma unroll
        for (int mi = 0; mi < 4; ++mi)
            #pragma unroll
            for (int c = 0; c < 2; ++c)
                af[mi][c] = *(const bf16x8*)(Ar + (wm + mi * 16 + l16) * 64 + (((quad + 4 * c) ^ sw) * 8));
        #pragma unroll
        for (int ni = 0; ni < 2; ++ni)
            #pragma unroll
            for (int c = 0; c < 2; ++c)
                bf[ni][c] = *(const bf16x8*)(Br + (wn + ni * 16 + l16) * 64 + (((quad + 4 * c) ^ sw) * 8));
        #pragma unroll
        for (int mi = 0; mi < 4; ++mi)
            #pragma unroll
            for (int ni = 0; ni < 2; ++ni) {
                acc[mi][ni] = __builtin_amdgcn_mfma_f32_16x16x32_bf16(af[mi][0], bf[ni][0], acc[mi][ni], 0, 0, 0);
                acc[mi][ni] = __builtin_amdgcn_mfma_f32_16x16x32_bf16(af[mi][1], bf[ni][1], acc[mi][ni], 0, 0, 0);
            }
        if (kt < 15) __syncthreads();
    }
#undef STG

    const float QS = 0.125f * 1.44269504088896f;
    #pragma unroll
    for (int ni = 0; ni < 2; ++ni) {
        int col = n0 + wn + ni * 16 + l16;
        int sect = col >> 10;
        int c = col & 1023;
        int h = c >> 6, dd = c & 63;
        #pragma unroll
        for (int mi = 0; mi < 4; ++mi) {
            #pragma unroll
            for (int r = 0; r < 4; ++r) {
                int m = m0 + wm + mi * 16 + quad * 4 + r;
                int b = m >> 10, i = m & 1023;
                float v = acc[mi][ni][r];
                if (sect == 0)      q[((b * 16 + h) * 1024 + i) * 64 + dd] = f2bf(v * QS);
                else if (sect == 1) kk[((b * 16 + h) * 1024 + i) * 64 + dd] = f2bf(v);
                else                vt[((b * 16 + h) * 64 + dd) * 1024 + i] = f2bf(v);
            }
        }
    }
}

// ---------------- proj GEMM: 512-thread dbuf dist-1 (frozen) ----------------
__global__ __launch_bounds__(512, 4) void gemm_proj5(const short* __restrict__ A,
                                                     const short* __restrict__ Bt,
                                                     const float* __restrict__ bias,
                                                     float* __restrict__ out) {
    extern __shared__ short lds[];          // A[2][128][64] | B[2][128][64]
    const int K = 1024;
    constexpr int NTX = 8;
    constexpr int NWG = 64 * NTX;           // 512
    constexpr int CHUNK = NWG / 8;

    const int bid = blockIdx.x;
    const int tile = (bid & 7) * CHUNK + (bid >> 3);
    const int m0 = (tile / NTX) * 128;
    const int n0 = (tile % NTX) * 128;

    const int t = threadIdx.x;
    const int w = t >> 6, lane = t & 63, quad = lane >> 4, l16 = lane & 15;
    const int wm = (w >> 2) * 64, wn = (w & 3) * 32;
    const int sw = l16 & 7;

    const int srow = t >> 3;
    const int scol = ((t & 7) ^ (srow & 7)) * 8;
    const short* Ag = A  + (m0 + srow) * K + scol;
    const short* Bg = Bt + (n0 + srow) * K + scol;
    const int w8 = w * 8 * 64;

    f32x4 acc[4][2];
    #pragma unroll
    for (int mi = 0; mi < 4; ++mi)
        #pragma unroll
        for (int ni = 0; ni < 2; ++ni) acc[mi][ni] = (f32x4){0.f, 0.f, 0.f, 0.f};

#define STG(kt_, d_) do { \
    _Pragma("unroll") \
    for (int r = 0; r < 2; ++r) \
        load_lds16(Ag + r * 64 * K + (kt_) * 64, lds + (d_) * 8192 + r * 64 * 64 + w8); \
    _Pragma("unroll") \
    for (int r = 0; r < 2; ++r) \
        load_lds16(Bg + r * 64 * K + (kt_) * 64, lds + 16384 + (d_) * 8192 + r * 64 * 64 + w8); } while (0)

    STG(0, 0);
    __syncthreads();

    #pragma unroll 1
    for (int kt = 0; kt < 16; ++kt) {
        const int d = kt & 1;
        if (kt < 15) STG(kt + 1, d ^ 1);

        const short* Ar = lds + d * 8192;
        const short* Br = lds + 16384 + d * 8192;
        bf16x8 af[4][2], bf[2][2];
        #pragma unroll
        for (int mi = 0; mi < 4; ++mi)
            #pragma unroll
            for (int c = 0; c < 2; ++c)
                af[mi][c] = *(const bf16x8*)(Ar + (wm + mi * 16 + l16) * 64 + (((quad + 4 * c) ^ sw) * 8));
        #pragma unroll
        for (int ni = 0; ni < 2; ++ni)
            #pragma unroll
            for (int c = 0; c < 2; ++c)
                bf[ni][c] = *(const bf16x8*)(Br + (wn + ni * 16 + l16) * 64 + (((quad + 4 * c) ^ sw) * 8));
        #pragma unroll
        for (int mi = 0; mi < 4; ++mi)
            #pragma unroll
            for (int ni = 0; ni < 2; ++ni) {
                acc[mi][ni] = __builtin_amdgcn_mfma_f32_16x16x32_bf16(af[mi][0], bf[ni][0], acc[mi][ni], 0, 0, 0);
                acc[mi][ni] = __builtin_amdgcn_mfma_f32_16x16x32_bf16(af[mi][1], bf[ni][1], acc[mi][ni], 0, 0, 0);
            }
        if (kt < 15) __syncthreads();
    }
#undef STG

    #pragma unroll
    for (int ni = 0; ni < 2; ++ni) {
        int col = n0 + wn + ni * 16 + l16;
        float bv = bias[col];
        #pragma unroll
        for (int mi = 0; mi < 4; ++mi) {
            #pragma unroll
            for (int r = 0; r < 4; ++r) {
                int m = m0 + wm + mi * 16 + quad * 4 + r;
                out[m * 1024 + col] = acc[mi][ni][r] + bv;
            }
        }
    }
}

// ---------------- Flash attention: 512-thr QBLK=256, dbuf K/V, register P ----------------
__global__ __launch_bounds__(512) void attn_kernel(const short* __restrict__ q,
                                                   const short* __restrict__ k,
                                                   const short* __restrict__ vt,
                                                   short* __restrict__ ao) {
    __shared__ alignas(16) short Ks[2][64][72];
    __shared__ alignas(16) short Vs[2][64][72];

    const int bh = blockIdx.y, qt = blockIdx.x;
    const int t = threadIdx.x, w = t >> 6, lane = t & 63, quad = lane >> 4, l16 = lane & 15;
    const short* qg = q  + (bh * 1024 + qt * 256) * 64;
    const short* kg = k  + bh * 65536;
    const short* vg = vt + bh * 65536;

    bf16x8 qf[2][2];
    for (int mi = 0; mi < 2; ++mi) {
        const short* qr = qg + (w * 32 + mi * 16 + l16) * 64;
        qf[mi][0] = *(const bf16x8*)(qr + quad * 8);
        qf[mi][1] = *(const bf16x8*)(qr + 32 + quad * 8);
    }

    const int r0 = t >> 3, c80 = (t & 7) * 8;          // 512 thr cover 64x64 in one shot

    float rs[2] = {0.f, 0.f};
    f32x4 oaccT[2][4];
    for (int mi = 0; mi < 2; ++mi)
        for (int dt = 0; dt < 4; ++dt) oaccT[mi][dt] = (f32x4){0.f, 0.f, 0.f, 0.f};

    {
        float4 a = *(const float4*)&kg[r0 * 64 + c80];
        float4 c = *(const float4*)&vg[r0 * 1024 + c80];
        *(float4*)&Ks[0][r0][c80] = a;
        *(float4*)&Vs[0][r0][c80] = c;
    }

    for (int jt = 0; jt < 16; ++jt) {
        const int cur = jt & 1;
        asm volatile("s_waitcnt lgkmcnt(0)" ::: "memory");
        asm volatile("s_barrier" ::: "memory");

        float4 kr0, vr0;
        if (jt < 15) {
            int jn = jt + 1;
            kr0 = *(const float4*)&kg[(jn * 64 + r0) * 64 + c80];
            vr0 = *(const float4*)&vg[r0 * 1024 + jn * 64 + c80];
        }

        for (int js = 0; js < 4; ++js) {
            bf16x8 kf0 = *(const bf16x8*)&Ks[cur][js * 16 + l16][quad * 8];
            bf16x8 kf1 = *(const bf16x8*)&Ks[cur][js * 16 + l16][32 + quad * 8];
            bf16x4 vtf[4];
            for (int dt = 0; dt < 4; ++dt)
                vtf[dt] = *(const bf16x4*)&Vs[cur][dt * 16 + l16][js * 16 + quad * 4];
            for (int mi = 0; mi < 2; ++mi) {
                f32x4 s = (f32x4){0.f, 0.f, 0.f, 0.f};
                __builtin_amdgcn_s_setprio(1);
                s = __builtin_amdgcn_mfma_f32_16x16x32_bf16(kf0, qf[mi][0], s, 0, 0, 0);
                s = __builtin_amdgcn_mfma_f32_16x16x32_bf16(kf1, qf[mi][1], s, 0, 0, 0);
                __builtin_amdgcn_s_setprio(0);
                bf16x4 pfrag;
                #pragma unroll
                for (int r = 0; r < 4; ++r) {
                    float p = __builtin_amdgcn_exp2f(s[r]);
                    rs[mi] += p;
                    pfrag[r] = f2bf_cvt(p);
                }
                __builtin_amdgcn_s_setprio(1);
                #pragma unroll
                for (int dt = 0; dt < 4; ++dt)
                    oaccT[mi][dt] = __builtin_amdgcn_mfma_f32_16x16x16bf16_1k(
                        vtf[dt], pfrag, oaccT[mi][dt], 0, 0, 0);
                __builtin_amdgcn_s_setprio(0);
            }
        }

        if (jt < 15) {
            const int nxt = cur ^ 1;
            *(float4*)&Ks[nxt][r0][c80] = kr0;
            *(float4*)&Vs[nxt][r0][c80] = vr0;
        }
    }

    for (int mi = 0; mi < 2; ++mi) {
        rs[mi] += __shfl_xor(rs[mi], 16, 64);
        rs[mi] += __shfl_xor(rs[mi], 32, 64);
    }

    const int b = bh >> 4, h = bh & 15;
    for (int mi = 0; mi < 2; ++mi) {
        float inv = 1.0f / rs[mi];
        int i = qt * 256 + w * 32 + mi * 16 + l16;
        short* aor = ao + (b * 1024 + i) * 1024 + h * 64;
        for (int dt = 0; dt < 4; ++dt) {
            bf16x4 o4;
            #pragma unroll
            for (int r = 0; r < 4; ++r) o4[r] = f2bf_cvt(oaccT[mi][dt][r] * inv);
            *(bf16x4*)(aor + dt * 16 + quad * 4) = o4;
        }
    }
}

extern "C" void kernel_launch(void* const* d_in, const int* in_sizes, int n_in,
                              void* d_out, int out_size, void* d_ws, size_t ws_size,
                              hipStream_t stream) {
    const float* x      = (const float*)d_in[0];
    const float* w_qkv  = (const float*)d_in[1];
    const float* w_proj = (const float*)d_in[2];
    const float* b_proj = (const float*)d_in[3];
    float* out = (float*)d_out;

    char* ws = (char*)d_ws;
    short* xb     = (short*)(ws);
    short* wqkvb  = (short*)(ws + 16777216);
    short* wprojb = (short*)(ws + 23068672);
    short* qb     = (short*)(ws + 25165824);
    short* kb     = (short*)(ws + 41943040);
    short* vtb    = (short*)(ws + 58720256);
    short* aob    = (short*)(ws + 75497472);

    static bool s_init = false;
    if (!s_init) {
        hipFuncSetAttribute(reinterpret_cast<const void*>(&gemm_qkv5),
                            hipFuncAttributeMaxDynamicSharedMemorySize, 65536);
        hipFuncSetAttribute(reinterpret_cast<const void*>(&gemm_proj5),
                            hipFuncAttributeMaxDynamicSharedMemorySize, 65536);
        s_init = true;
    }

    convert_all<<<12288, 256, 0, stream>>>(x, w_qkv, w_proj, xb, wqkvb, wprojb);
    gemm_qkv5<<<1536, 512, 65536, stream>>>(xb, wqkvb, qb, kb, vtb);
    // attn: QBLK=256 -> grid (4, 128), 512 threads
    attn_kernel<<<dim3(4, 128), 512, 0, stream>>>(qb, kb, vtb, aob);
    gemm_proj5<<<512, 512, 65536, stream>>>(aob, wprojb, b_proj, out);
}